// Round 2
// baseline (66.584 us; speedup 1.0000x reference)
//
#include <hip/hip_runtime.h>
#include <math.h>

#define OBS 2264
#define ACT 32
#define HID 4096
#define VOX 216
#define PRE (OBS - VOX)   // 2048
#define N4_OBS (OBS / 4)  // 566
#define N4_HID (HID / 4)  // 1024

// ---------------------------------------------------------------------------
// K_A: fused conv3d-chain + input-norm + GEMV W0 + tanh.
// One block per output row (4096 blocks, 256 threads). Every block redundantly
// recomputes the tiny 6x6x6 conv chain (35 KFLOP) in LDS — aggregate cost
// ~143 MFLOP ≈ 1 µs chip-wide, hidden under the W0 row streaming. This removes
// the serial 1-block conv kernel node entirely.
// ---------------------------------------------------------------------------
__global__ __launch_bounds__(256) void fused0_kernel(
    const float* __restrict__ x,
    const float* __restrict__ cw0, const float* __restrict__ cb0,
    const float* __restrict__ cw1, const float* __restrict__ cb1,
    const float* __restrict__ cw2, const float* __restrict__ cb2,
    const float* __restrict__ cw3, const float* __restrict__ cb3,
    const float* __restrict__ cw4, const float* __restrict__ cb4,
    const float* __restrict__ cw5, const float* __restrict__ cb5,
    const float* __restrict__ in_shift, const float* __restrict__ in_scale,
    const float* __restrict__ W0, const float* __restrict__ b0,
    float* __restrict__ h0)
{
    __shared__ float vb[2][VOX];
    __shared__ __align__(16) float su[OBS];   // normalized input vector
    __shared__ float part[4];

    const int tid = threadIdx.x;

    if (tid < VOX) vb[0][tid] = x[PRE + tid];
    __syncthreads();

    const float* ws[6] = {cw0, cw1, cw2, cw3, cw4, cw5};
    const float* bs[6] = {cb0, cb1, cb2, cb3, cb4, cb5};

    int cur = 0;
    #pragma unroll 1
    for (int l = 0; l < 6; ++l) {
        if (tid < VOX) {
            const int d = tid / 36;
            const int h = (tid / 6) % 6;
            const int w = tid % 6;
            const float* k = ws[l];
            float acc = bs[l][0];
            #pragma unroll
            for (int kd = 0; kd < 3; ++kd) {
                const int dd = d + kd - 1;
                if (dd < 0 || dd > 5) continue;
                #pragma unroll
                for (int kh = 0; kh < 3; ++kh) {
                    const int hh = h + kh - 1;
                    if (hh < 0 || hh > 5) continue;
                    #pragma unroll
                    for (int kw = 0; kw < 3; ++kw) {
                        const int ww = w + kw - 1;
                        if (ww < 0 || ww > 5) continue;
                        acc += k[kd * 9 + kh * 3 + kw] * vb[cur][dd * 36 + hh * 6 + ww];
                    }
                }
            }
            vb[cur ^ 1][tid] = fmaxf(acc, 0.f);
        }
        cur ^= 1;
        __syncthreads();
    }

    // normalized input vector into LDS
    for (int i = tid; i < OBS; i += 256) {
        const float val = (i < PRE) ? x[i] : vb[cur][i - PRE];
        su[i] = (val - in_shift[i]) / (in_scale[i] + 1e-8f);
    }
    __syncthreads();

    // GEMV row dot: W0[row, :] . su
    const int row = blockIdx.x;
    const float4* __restrict__ Wr = reinterpret_cast<const float4*>(W0 + (size_t)row * OBS);
    const float4* __restrict__ u4 = reinterpret_cast<const float4*>(su);

    float acc = 0.f;
    for (int j = tid; j < N4_OBS; j += 256) {
        const float4 wv = Wr[j];
        const float4 uv = u4[j];
        acc += wv.x * uv.x + wv.y * uv.y + wv.z * uv.z + wv.w * uv.w;
    }
    #pragma unroll
    for (int off = 32; off > 0; off >>= 1) acc += __shfl_down(acc, off, 64);

    if ((tid & 63) == 0) part[tid >> 6] = acc;
    __syncthreads();
    if (tid == 0) {
        const float s = part[0] + part[1] + part[2] + part[3] + b0[row];
        h0[row] = tanhf(s);
    }
}

// ---------------------------------------------------------------------------
// K_B: GEMV W1 [4096,4096] + tanh. One block per row.
// ---------------------------------------------------------------------------
__global__ __launch_bounds__(256) void gemv1_kernel(
    const float* __restrict__ W, const float* __restrict__ b,
    const float* __restrict__ u, float* __restrict__ out)
{
    const int row = blockIdx.x;
    const int tid = threadIdx.x;
    const float4* __restrict__ Wr = reinterpret_cast<const float4*>(W + (size_t)row * HID);
    const float4* __restrict__ u4 = reinterpret_cast<const float4*>(u);

    float acc = 0.f;
    #pragma unroll 4
    for (int j = tid; j < N4_HID; j += 256) {
        const float4 wv = Wr[j];
        const float4 uv = u4[j];
        acc += wv.x * uv.x + wv.y * uv.y + wv.z * uv.z + wv.w * uv.w;
    }
    #pragma unroll
    for (int off = 32; off > 0; off >>= 1) acc += __shfl_down(acc, off, 64);

    __shared__ float part[4];
    if ((tid & 63) == 0) part[tid >> 6] = acc;
    __syncthreads();
    if (tid == 0) {
        const float s = part[0] + part[1] + part[2] + part[3] + b[row];
        out[row] = tanhf(s);
    }
}

// ---------------------------------------------------------------------------
// K_C: final GEMV [32,4096] + output affine.
// ---------------------------------------------------------------------------
__global__ __launch_bounds__(256) void gemv_out_kernel(
    const float* __restrict__ W, const float* __restrict__ b,
    const float* __restrict__ u,
    const float* __restrict__ oscale, const float* __restrict__ oshift,
    float* __restrict__ out)
{
    const int row = blockIdx.x;
    const int tid = threadIdx.x;
    const float4* __restrict__ Wr = reinterpret_cast<const float4*>(W + (size_t)row * HID);
    const float4* __restrict__ u4 = reinterpret_cast<const float4*>(u);

    float acc = 0.f;
    #pragma unroll 4
    for (int j = tid; j < N4_HID; j += 256) {
        const float4 wv = Wr[j];
        const float4 uv = u4[j];
        acc += wv.x * uv.x + wv.y * uv.y + wv.z * uv.z + wv.w * uv.w;
    }
    #pragma unroll
    for (int off = 32; off > 0; off >>= 1) acc += __shfl_down(acc, off, 64);

    __shared__ float part[4];
    if ((tid & 63) == 0) part[tid >> 6] = acc;
    __syncthreads();
    if (tid == 0) {
        const float s = part[0] + part[1] + part[2] + part[3] + b[row];
        out[row] = s * oscale[row] + oshift[row];
    }
}

extern "C" void kernel_launch(void* const* d_in, const int* in_sizes, int n_in,
                              void* d_out, int out_size, void* d_ws, size_t ws_size,
                              hipStream_t stream) {
    const float* x = (const float*)d_in[0];

    // setup_inputs() dict order interleaves cw_i/cb_i; detect defensively.
    const float* cw[6];
    const float* cb[6];
    if (in_sizes[2] == 1) {           // interleaved: x, cw0, cb0, cw1, cb1, ...
        for (int i = 0; i < 6; ++i) {
            cw[i] = (const float*)d_in[1 + 2 * i];
            cb[i] = (const float*)d_in[2 + 2 * i];
        }
    } else {                          // grouped: x, cw0..cw5, cb0..cb5
        for (int i = 0; i < 6; ++i) {
            cw[i] = (const float*)d_in[1 + i];
            cb[i] = (const float*)d_in[7 + i];
        }
    }
    const float* W0       = (const float*)d_in[13];
    const float* b0       = (const float*)d_in[14];
    const float* W1       = (const float*)d_in[15];
    const float* b1       = (const float*)d_in[16];
    const float* W2       = (const float*)d_in[17];
    const float* b2       = (const float*)d_in[18];
    const float* in_shift = (const float*)d_in[19];
    const float* in_scale = (const float*)d_in[20];
    const float* oshift   = (const float*)d_in[21];
    const float* oscale   = (const float*)d_in[22];

    float* ws = (float*)d_ws;
    float* h0 = ws;            // [0, 4096)
    float* h1 = ws + 4096;     // [4096, 8192)
    float* y  = (float*)d_out;

    fused0_kernel<<<HID, 256, 0, stream>>>(
        x, cw[0], cb[0], cw[1], cb[1], cw[2], cb[2],
        cw[3], cb[3], cw[4], cb[4], cw[5], cb[5],
        in_shift, in_scale, W0, b0, h0);

    gemv1_kernel<<<HID, 256, 0, stream>>>(W1, b1, h0, h1);
    gemv_out_kernel<<<ACT, 256, 0, stream>>>(W2, b2, h1, oscale, oshift, y);
}

// Round 3
// 40.476 us; speedup vs baseline: 1.6450x; 1.6450x over previous
//
#include <hip/hip_runtime.h>
#include <math.h>

#define OBS 2264
#define ACT 32
#define HID 4096
#define VOX 216
#define PRE (OBS - VOX)   // 2048
#define N4_OBS (OBS / 4)  // 566
#define N4_HID (HID / 4)  // 1024
#define ROWS 4            // rows per block in fused0 / gemv1

// ---------------------------------------------------------------------------
// K_A: fused conv3d-chain + input-norm + GEMV W0 (4 rows/block) + tanh.
// 1024 blocks x 256 threads. Conv weights staged to LDS; the 6-layer loop is
// FULLY UNROLLED with compile-time layer indices — no runtime-indexed pointer
// arrays (those go to scratch: rule #20, the R1 regression).
// ---------------------------------------------------------------------------
__global__ __launch_bounds__(256) void fused0_kernel(
    const float* __restrict__ x,
    const float* __restrict__ cw0, const float* __restrict__ cb0,
    const float* __restrict__ cw1, const float* __restrict__ cb1,
    const float* __restrict__ cw2, const float* __restrict__ cb2,
    const float* __restrict__ cw3, const float* __restrict__ cb3,
    const float* __restrict__ cw4, const float* __restrict__ cb4,
    const float* __restrict__ cw5, const float* __restrict__ cb5,
    const float* __restrict__ in_shift, const float* __restrict__ in_scale,
    const float* __restrict__ W0, const float* __restrict__ b0,
    float* __restrict__ h0)
{
    __shared__ float skw[6][27];
    __shared__ float skb[6];
    __shared__ float vbA[VOX], vbB[VOX];
    __shared__ __align__(16) float su[OBS];
    __shared__ float part[ROWS][4];

    const int tid = threadIdx.x;

    // one-time staging: conv weights/biases -> LDS; voxel tail -> vbA
    if (tid < 27)        skw[0][tid]       = cw0[tid];
    else if (tid < 54)   skw[1][tid - 27]  = cw1[tid - 27];
    else if (tid < 81)   skw[2][tid - 54]  = cw2[tid - 54];
    else if (tid < 108)  skw[3][tid - 81]  = cw3[tid - 81];
    else if (tid < 135)  skw[4][tid - 108] = cw4[tid - 108];
    else if (tid < 162)  skw[5][tid - 135] = cw5[tid - 135];
    else if (tid == 162) skb[0] = cb0[0];
    else if (tid == 163) skb[1] = cb1[0];
    else if (tid == 164) skb[2] = cb2[0];
    else if (tid == 165) skb[3] = cb3[0];
    else if (tid == 166) skb[4] = cb4[0];
    else if (tid == 167) skb[5] = cb5[0];
    if (tid < VOX) vbA[tid] = x[PRE + tid];
    __syncthreads();

    const int d = tid / 36;
    const int h = (tid / 6) % 6;
    const int w = tid % 6;

    // compile-time layer index L -> all LDS indices static
#define CONV_LAYER(L, SRC, DST)                                              \
    if (tid < VOX) {                                                         \
        float acc = skb[L];                                                  \
        _Pragma("unroll") for (int kd = 0; kd < 3; ++kd) {                   \
            const int dd = d + kd - 1;                                       \
            if (dd >= 0 && dd <= 5) {                                        \
                _Pragma("unroll") for (int kh = 0; kh < 3; ++kh) {           \
                    const int hh = h + kh - 1;                               \
                    if (hh >= 0 && hh <= 5) {                                \
                        _Pragma("unroll") for (int kw2 = 0; kw2 < 3; ++kw2) {\
                            const int ww = w + kw2 - 1;                      \
                            if (ww >= 0 && ww <= 5)                          \
                                acc += skw[L][kd * 9 + kh * 3 + kw2]         \
                                     * SRC[dd * 36 + hh * 6 + ww];           \
                        }                                                    \
                    }                                                        \
                }                                                            \
            }                                                                \
        }                                                                    \
        DST[tid] = fmaxf(acc, 0.f);                                          \
    }                                                                        \
    __syncthreads();

    CONV_LAYER(0, vbA, vbB)
    CONV_LAYER(1, vbB, vbA)
    CONV_LAYER(2, vbA, vbB)
    CONV_LAYER(3, vbB, vbA)
    CONV_LAYER(4, vbA, vbB)
    CONV_LAYER(5, vbB, vbA)
#undef CONV_LAYER
    // result in vbA

    for (int i = tid; i < OBS; i += 256) {
        const float val = (i < PRE) ? x[i] : vbA[i - PRE];
        su[i] = (val - in_shift[i]) / (in_scale[i] + 1e-8f);
    }
    __syncthreads();

    // 4-row GEMV: W0[row0+r, :] . su
    const int row0 = blockIdx.x * ROWS;
    const float4* __restrict__ u4 = reinterpret_cast<const float4*>(su);
    const float4* __restrict__ W4 = reinterpret_cast<const float4*>(W0);
    const size_t rstride4 = OBS / 4;   // 566

    float accs[ROWS] = {0.f, 0.f, 0.f, 0.f};
    for (int j = tid; j < N4_OBS; j += 256) {
        const float4 uv = u4[j];
        #pragma unroll
        for (int r = 0; r < ROWS; ++r) {
            const float4 wv = W4[(size_t)(row0 + r) * rstride4 + j];
            accs[r] += wv.x * uv.x + wv.y * uv.y + wv.z * uv.z + wv.w * uv.w;
        }
    }
    #pragma unroll
    for (int r = 0; r < ROWS; ++r) {
        float a = accs[r];
        #pragma unroll
        for (int off = 32; off > 0; off >>= 1) a += __shfl_down(a, off, 64);
        if ((tid & 63) == 0) part[r][tid >> 6] = a;
    }
    __syncthreads();
    if (tid < ROWS) {
        const float s = part[tid][0] + part[tid][1] + part[tid][2] + part[tid][3]
                      + b0[row0 + tid];
        h0[row0 + tid] = tanhf(s);
    }
}

// ---------------------------------------------------------------------------
// K_B: GEMV W1 [4096,4096] + tanh, 4 rows/block (1024 blocks x 256).
// ---------------------------------------------------------------------------
__global__ __launch_bounds__(256) void gemv1_kernel(
    const float* __restrict__ W, const float* __restrict__ b,
    const float* __restrict__ u, float* __restrict__ out)
{
    const int row0 = blockIdx.x * ROWS;
    const int tid = threadIdx.x;
    const float4* __restrict__ u4 = reinterpret_cast<const float4*>(u);
    const float4* __restrict__ W4 = reinterpret_cast<const float4*>(W);

    float accs[ROWS] = {0.f, 0.f, 0.f, 0.f};
    for (int j = tid; j < N4_HID; j += 256) {
        const float4 uv = u4[j];
        #pragma unroll
        for (int r = 0; r < ROWS; ++r) {
            const float4 wv = W4[(size_t)(row0 + r) * N4_HID + j];
            accs[r] += wv.x * uv.x + wv.y * uv.y + wv.z * uv.z + wv.w * uv.w;
        }
    }
    __shared__ float part[ROWS][4];
    #pragma unroll
    for (int r = 0; r < ROWS; ++r) {
        float a = accs[r];
        #pragma unroll
        for (int off = 32; off > 0; off >>= 1) a += __shfl_down(a, off, 64);
        if ((tid & 63) == 0) part[r][tid >> 6] = a;
    }
    __syncthreads();
    if (tid < ROWS) {
        const float s = part[tid][0] + part[tid][1] + part[tid][2] + part[tid][3]
                      + b[row0 + tid];
        out[row0 + tid] = tanhf(s);
    }
}

// ---------------------------------------------------------------------------
// K_C: final GEMV [32,4096] + output affine. 32 blocks x 1024 threads,
// exactly one float4 per thread.
// ---------------------------------------------------------------------------
__global__ __launch_bounds__(1024) void gemv_out_kernel(
    const float* __restrict__ W, const float* __restrict__ b,
    const float* __restrict__ u,
    const float* __restrict__ oscale, const float* __restrict__ oshift,
    float* __restrict__ out)
{
    const int row = blockIdx.x;
    const int tid = threadIdx.x;
    const float4* __restrict__ Wr = reinterpret_cast<const float4*>(W + (size_t)row * HID);
    const float4* __restrict__ u4 = reinterpret_cast<const float4*>(u);

    const float4 wv = Wr[tid];
    const float4 uv = u4[tid];
    float a = wv.x * uv.x + wv.y * uv.y + wv.z * uv.z + wv.w * uv.w;

    #pragma unroll
    for (int off = 32; off > 0; off >>= 1) a += __shfl_down(a, off, 64);

    __shared__ float part[16];
    if ((tid & 63) == 0) part[tid >> 6] = a;
    __syncthreads();
    if (tid == 0) {
        float s = b[row];
        #pragma unroll
        for (int i = 0; i < 16; ++i) s += part[i];
        out[row] = s * oscale[row] + oshift[row];
    }
}

extern "C" void kernel_launch(void* const* d_in, const int* in_sizes, int n_in,
                              void* d_out, int out_size, void* d_ws, size_t ws_size,
                              hipStream_t stream) {
    const float* x = (const float*)d_in[0];

    const float* cw[6];
    const float* cb[6];
    if (in_sizes[2] == 1) {           // interleaved: x, cw0, cb0, cw1, cb1, ...
        for (int i = 0; i < 6; ++i) {
            cw[i] = (const float*)d_in[1 + 2 * i];
            cb[i] = (const float*)d_in[2 + 2 * i];
        }
    } else {                          // grouped: x, cw0..cw5, cb0..cb5
        for (int i = 0; i < 6; ++i) {
            cw[i] = (const float*)d_in[1 + i];
            cb[i] = (const float*)d_in[7 + i];
        }
    }
    const float* W0       = (const float*)d_in[13];
    const float* b0       = (const float*)d_in[14];
    const float* W1       = (const float*)d_in[15];
    const float* b1       = (const float*)d_in[16];
    const float* W2       = (const float*)d_in[17];
    const float* b2       = (const float*)d_in[18];
    const float* in_shift = (const float*)d_in[19];
    const float* in_scale = (const float*)d_in[20];
    const float* oshift   = (const float*)d_in[21];
    const float* oscale   = (const float*)d_in[22];

    float* ws = (float*)d_ws;
    float* h0 = ws;            // [0, 4096)
    float* h1 = ws + 4096;     // [4096, 8192)
    float* y  = (float*)d_out;

    fused0_kernel<<<HID / ROWS, 256, 0, stream>>>(
        x, cw[0], cb[0], cw[1], cb[1], cw[2], cb[2],
        cw[3], cb[3], cw[4], cb[4], cw[5], cb[5],
        in_shift, in_scale, W0, b0, h0);

    gemv1_kernel<<<HID / ROWS, 256, 0, stream>>>(W1, b1, h0, h1);
    gemv_out_kernel<<<ACT, 1024, 0, stream>>>(W2, b2, h1, oscale, oshift, y);
}